// Round 5
// baseline (157.799 us; speedup 1.0000x reference)
//
#include <hip/hip_runtime.h>
#include <math.h>

// CellSegmentationLoss: fused focal + dice + boundary-BCE + IoU-aux loss.
// Inputs: d_in[0]=pred_masks (16*1*1024*1024 f32), d_in[1]=gt_masks (same),
//         d_in[2]=pred_iou (16 f32). Output: 1 f32 scalar.
//
// R5: INTERLEAVED grid-stride access (the one structural difference vs the
// 6.29 TB/s copy ubench). R1-R4 gave each block a private contiguous slab
// (8-32 KB apart) -> concurrent streams at large power-of-2 strides can
// alias HBM channels. Here the 256 blocks of an image read a dense sliding
// 1 MB window: block-stride float4, 4 iterations. Compute identical to R3.
// No atomics, no memset: per-block partials + finalize kernel.

#define HW_PIX (1024 * 1024)
#define BATCH 16
constexpr int BPI = 256;                       // blocks per image
constexpr int GRID = BATCH * BPI;              // 4096
constexpr int THREADS = 256;
constexpr int STRIDE_PX = BPI * THREADS * 4;   // 262144 px per sweep
constexpr int ITERS = HW_PIX / STRIDE_PX;      // 4

__global__ __launch_bounds__(THREADS) void
loss_partial(const float* __restrict__ x, const float* __restrict__ t,
             float* __restrict__ acc) {
  const int b = blockIdx.x >> 8;               // image index (BPI=256)
  const int chunk = blockIdx.x & (BPI - 1);
  // Interleaved: consecutive blocks own adjacent 4 KB stripes; the 256
  // blocks of an image cover a dense 1 MB window that slides 4x.
  const long base =
      (long)b * HW_PIX + ((long)chunk * THREADS + threadIdx.x) * 4;

  float fsum = 0.f, csum = 0.f, isum = 0.f, psum = 0.f;
  unsigned tcnt = 0, bicnt = 0, bpcnt = 0;     // wave-uniform ballot counts

#pragma unroll
  for (int i = 0; i < ITERS; ++i) {
    const float4 xv = *(const float4*)(x + base + (long)i * STRIDE_PX);
    const float4 tv = *(const float4*)(t + base + (long)i * STRIDE_PX);
    const float* xs = reinterpret_cast<const float*>(&xv);
    const float* ts = reinterpret_cast<const float*>(&tv);
#pragma unroll
    for (int j = 0; j < 4; ++j) {
      const float xx = xs[j];
      const float tt = ts[j];
      const float e = __expf(-fabsf(xx));      // exp(-|x|) in (0,1]
      const float sp = 1.0f + e;
      const float r = __builtin_amdgcn_rcpf(sp);
      const float p = (xx >= 0.0f) ? r : e * r; // sigmoid(x)
      const float ce = fmaxf(xx, 0.0f) - xx * tt + __logf(sp);
      const float om = fmaf(tt, 1.0f - 2.0f * p, p); // 1 - p_t
      const float at = 0.75f - 0.5f * tt;            // alpha_t
      fsum += at * ce * om * om;
      csum += ce;
      isum = fmaf(p, tt, isum);
      psum += p;
      const unsigned long long mt = __ballot(tt != 0.0f);
      const unsigned long long mb = __ballot(xx > 0.0f); // p>0.5 <=> x>0
      tcnt += (unsigned)__popcll(mt);
      bpcnt += (unsigned)__popcll(mb);
      bicnt += (unsigned)__popcll(mt & mb);
    }
  }

  __shared__ float red[THREADS / 64][7];
  const int lane = threadIdx.x & 63;
  const int wave = threadIdx.x >> 6;
  float vals[4] = {fsum, csum, isum, psum};
#pragma unroll
  for (int k = 0; k < 4; ++k) {
    float v = vals[k];
#pragma unroll
    for (int off = 32; off > 0; off >>= 1) v += __shfl_down(v, off);
    if (lane == 0) red[wave][k] = v;
  }
  if (lane == 0) {                  // ballot counts are already wave totals
    red[wave][4] = (float)tcnt;
    red[wave][5] = (float)bicnt;
    red[wave][6] = (float)bpcnt;
  }
  __syncthreads();
  if (threadIdx.x < 7) {
    acc[blockIdx.x * 7 + threadIdx.x] =
        red[0][threadIdx.x] + red[1][threadIdx.x] +
        red[2][threadIdx.x] + red[3][threadIdx.x];
  }
}

__global__ void loss_final(const float* __restrict__ acc,
                           const float* __restrict__ pred_iou,
                           float* __restrict__ out) {
  constexpr float SMOOTH = 1e-6f;
  __shared__ float fin[BATCH][7];
  const int tid = threadIdx.x;
  if (tid < BATCH * 7) {            // sum BPI block-partials per (b,k)
    const int b = tid / 7, k = tid % 7;
    float s = 0.f;
    for (int i = 0; i < BPI; ++i)
      s += acc[(b * BPI + i) * 7 + k];
    fin[b][k] = s;
  }
  __syncthreads();
  if (tid < 64) {
    const int lane = tid;           // lanes 0..15 carry batches
    float F = 0.f, C = 0.f, D = 0.f, Q = 0.f;
    if (lane < BATCH) {
      F = fin[lane][0];
      C = fin[lane][1];
      const float I = fin[lane][2], P = fin[lane][3], T = fin[lane][4],
                  BI = fin[lane][5], BP = fin[lane][6];
      D = (2.0f * I + SMOOTH) / (P + T + SMOOTH);   // dice term
      const float iou = (BI + SMOOTH) / (BP + T - BI + SMOOTH);
      const float d = pred_iou[lane] - iou;
      Q = d * d;
    }
#pragma unroll
    for (int off = 32; off > 0; off >>= 1) {
      F += __shfl_down(F, off);
      C += __shfl_down(C, off);
      D += __shfl_down(D, off);
      Q += __shfl_down(Q, off);
    }
    if (lane == 0) {
      const float invN = 1.0f / (float)((long)BATCH * HW_PIX);
      const float focal = F * invN;
      const float dice = 1.0f - D * (1.0f / (float)BATCH);
      const float half_boundary = C * invN; // 0.5 * (2.0 * mean(ce))
      const float iou_loss = Q * (1.0f / (float)BATCH);
      out[0] = focal + dice + half_boundary + 0.1f * iou_loss;
    }
  }
}

extern "C" void kernel_launch(void* const* d_in, const int* in_sizes, int n_in,
                              void* d_out, int out_size, void* d_ws,
                              size_t ws_size, hipStream_t stream) {
  const float* x = (const float*)d_in[0];
  const float* t = (const float*)d_in[1];
  const float* piou = (const float*)d_in[2];
  float* acc = (float*)d_ws;        // GRID*7 floats of block partials

  loss_partial<<<GRID, THREADS, 0, stream>>>(x, t, acc);
  loss_final<<<1, 128, 0, stream>>>(acc, piou, (float*)d_out);
}

// Round 8
// 150.895 us; speedup vs baseline: 1.0458x; 1.0458x over previous
//
#include <hip/hip_runtime.h>
#include <math.h>

// CellSegmentationLoss: fused focal + dice + boundary-BCE + IoU-aux loss.
// Inputs: d_in[0]=pred_masks (16*1*1024*1024 f32), d_in[1]=gt_masks (same),
//         d_in[2]=pred_iou (16 f32). Output: 1 f32 scalar.
//
// R8 (= R6/R7 compile-fixed): decisive per-wave MLP test. HIP float4 is a
// STRUCT -> indirect asm operand -> tied "+v" unsupported. ext_vector_type(4)
// float is a native <4 x float> (VReg_128), direct operand, ties fine.
// 16 global_load_dwordx4 issued via inline asm (pinned, unsinkable), consumed
// under explicit s_waitcnt vmcnt(14..0): 14 loads in flight per wave.

#define HW_PIX (1024 * 1024)
#define BATCH 16
constexpr int BPI = 128;                         // blocks per image
constexpr int GRID = BATCH * BPI;                // 2048
constexpr int THREADS = 256;
constexpr unsigned SWEEP_B = BPI * THREADS * 16; // byte stride per pair-step

typedef float vf4 __attribute__((ext_vector_type(4)));   // direct VReg_128

__global__ __launch_bounds__(THREADS) void
loss_partial(const float* __restrict__ x, const float* __restrict__ t,
             float* __restrict__ acc) {
  const int b = blockIdx.x >> 7;                 // image (BPI=128)
  const int chunk = blockIdx.x & (BPI - 1);
  const float* xb = x + (long)b * HW_PIX;        // uniform -> SGPR pair
  const float* tb = t + (long)b * HW_PIX;
  const unsigned off0 = (chunk * THREADS + threadIdx.x) * 16u;

  vf4 x0, x1, x2, x3, x4, x5, x6, x7;
  vf4 t0, t1, t2, t3, t4, t5, t6, t7;

  // Issue all 16 loads back-to-back; outputs pinned in 64 VGPRs.
#define ISSUE(i, xi, ti)                                              \
  asm volatile("global_load_dwordx4 %0, %2, %3\n\t"                   \
               "global_load_dwordx4 %1, %2, %4"                       \
               : "=v"(xi), "=v"(ti)                                   \
               : "v"(off0 + (unsigned)(i) * SWEEP_B), "s"(xb), "s"(tb));
  ISSUE(0, x0, t0) ISSUE(1, x1, t1) ISSUE(2, x2, t2) ISSUE(3, x3, t3)
  ISSUE(4, x4, t4) ISSUE(5, x5, t5) ISSUE(6, x6, t6) ISSUE(7, x7, t7)
#undef ISSUE

  float fsum = 0.f, csum = 0.f, isum = 0.f, psum = 0.f;
  unsigned tcnt = 0, bicnt = 0, bpcnt = 0;       // wave-uniform ballot counts

  auto compute = [&](const vf4& xv, const vf4& tv) {
#pragma unroll
    for (int j = 0; j < 4; ++j) {
      const float xx = xv[j];
      const float tt = tv[j];
      const float e = __expf(-fabsf(xx));        // exp(-|x|) in (0,1]
      const float sp = 1.0f + e;
      const float r = __builtin_amdgcn_rcpf(sp);
      const float p = (xx >= 0.0f) ? r : e * r;  // sigmoid(x)
      const float ce = fmaxf(xx, 0.0f) - xx * tt + __logf(sp);
      const float om = fmaf(tt, 1.0f - 2.0f * p, p); // 1 - p_t
      const float at = 0.75f - 0.5f * tt;            // alpha_t
      fsum += at * ce * om * om;
      csum += ce;
      isum = fmaf(p, tt, isum);
      psum += p;
      const unsigned long long mt = __ballot(tt != 0.0f);
      const unsigned long long mb = __ballot(xx > 0.0f); // p>0.5 <=> x>0
      tcnt += (unsigned)__popcll(mt);
      bpcnt += (unsigned)__popcll(mb);
      bicnt += (unsigned)__popcll(mt & mb);
    }
  };

  // Wait only for the oldest pair (vmcnt = still-outstanding loads). Tied
  // "+v" on the pair orders the wait after its loads and compute (which
  // reads the asm's SSA outputs) after the wait.
#define CONSUME(n, xi, ti)                                            \
  asm volatile("s_waitcnt vmcnt(" #n ")" : "+v"(xi), "+v"(ti));       \
  compute(xi, ti);
  CONSUME(14, x0, t0)
  CONSUME(12, x1, t1)
  CONSUME(10, x2, t2)
  CONSUME(8, x3, t3)
  CONSUME(6, x4, t4)
  CONSUME(4, x5, t5)
  CONSUME(2, x6, t6)
  CONSUME(0, x7, t7)
#undef CONSUME

  // Block reduction: wave shuffle -> LDS -> 7 per-block partials.
  __shared__ float red[THREADS / 64][7];
  const int lane = threadIdx.x & 63;
  const int wave = threadIdx.x >> 6;
  float vals[4] = {fsum, csum, isum, psum};
#pragma unroll
  for (int k = 0; k < 4; ++k) {
    float v = vals[k];
#pragma unroll
    for (int off2 = 32; off2 > 0; off2 >>= 1) v += __shfl_down(v, off2);
    if (lane == 0) red[wave][k] = v;
  }
  if (lane == 0) {                   // ballot counts are already wave totals
    red[wave][4] = (float)tcnt;
    red[wave][5] = (float)bicnt;
    red[wave][6] = (float)bpcnt;
  }
  __syncthreads();
  if (threadIdx.x < 7) {
    acc[blockIdx.x * 7 + threadIdx.x] =
        red[0][threadIdx.x] + red[1][threadIdx.x] +
        red[2][threadIdx.x] + red[3][threadIdx.x];
  }
}

__global__ void loss_final(const float* __restrict__ acc,
                           const float* __restrict__ pred_iou,
                           float* __restrict__ out) {
  constexpr float SMOOTH = 1e-6f;
  __shared__ float fin[BATCH][7];
  const int tid = threadIdx.x;
  if (tid < BATCH * 7) {             // sum BPI block-partials per (b,k)
    const int b = tid / 7, k = tid % 7;
    float s = 0.f;
    for (int i = 0; i < BPI; ++i)
      s += acc[(b * BPI + i) * 7 + k];
    fin[b][k] = s;
  }
  __syncthreads();
  if (tid < 64) {
    const int lane = tid;            // lanes 0..15 carry batches
    float F = 0.f, C = 0.f, D = 0.f, Q = 0.f;
    if (lane < BATCH) {
      F = fin[lane][0];
      C = fin[lane][1];
      const float I = fin[lane][2], P = fin[lane][3], T = fin[lane][4],
                  BI = fin[lane][5], BP = fin[lane][6];
      D = (2.0f * I + SMOOTH) / (P + T + SMOOTH);    // dice term
      const float iou = (BI + SMOOTH) / (BP + T - BI + SMOOTH);
      const float d = pred_iou[lane] - iou;
      Q = d * d;
    }
#pragma unroll
    for (int off = 32; off > 0; off >>= 1) {
      F += __shfl_down(F, off);
      C += __shfl_down(C, off);
      D += __shfl_down(D, off);
      Q += __shfl_down(Q, off);
    }
    if (lane == 0) {
      const float invN = 1.0f / (float)((long)BATCH * HW_PIX);
      const float focal = F * invN;
      const float dice = 1.0f - D * (1.0f / (float)BATCH);
      const float half_boundary = C * invN;  // 0.5 * (2.0 * mean(ce))
      const float iou_loss = Q * (1.0f / (float)BATCH);
      out[0] = focal + dice + half_boundary + 0.1f * iou_loss;
    }
  }
}

extern "C" void kernel_launch(void* const* d_in, const int* in_sizes, int n_in,
                              void* d_out, int out_size, void* d_ws,
                              size_t ws_size, hipStream_t stream) {
  const float* x = (const float*)d_in[0];
  const float* t = (const float*)d_in[1];
  const float* piou = (const float*)d_in[2];
  float* acc = (float*)d_ws;         // GRID*7 floats of block partials

  loss_partial<<<GRID, THREADS, 0, stream>>>(x, t, acc);
  loss_final<<<1, 128, 0, stream>>>(acc, piou, (float*)d_out);
}